// Round 11
// baseline (194.375 us; speedup 1.0000x reference)
//
#include <hip/hip_runtime.h>

typedef _Float16 half8 __attribute__((ext_vector_type(8)));
typedef _Float16 half4 __attribute__((ext_vector_type(4)));
typedef float f32x4 __attribute__((ext_vector_type(4)));

#define GLOAD16(gptr, lptr)                                                               \
  __builtin_amdgcn_global_load_lds((const __attribute__((address_space(1))) void*)(gptr), \
                                   (__attribute__((address_space(3))) void*)(lptr), 16, 0, 0)

// compiler-level memory fence (no instructions): pins LDS/global op ordering
// around raw s_barrier, which is NOT an IR-level memory fence.
#define MEMFENCE asm volatile("" ::: "memory")

// 2^x on the native TRANS pipe via the builtin (compiler inserts the required
// TRANS-hazard wait states; raw inline-asm v_exp_f32 NaN'd in R9).
__device__ __forceinline__ float exp2_fast(float x) {
#if __has_builtin(__builtin_amdgcn_exp2f)
  return __builtin_amdgcn_exp2f(x);
#else
  float r;
  asm("v_exp_f32 %0, %1\n\ts_nop 3" : "=v"(r) : "v"(x));
  return r;
#endif
}

constexpr int B_ = 4, S_ = 2048, D_ = 1024;
constexpr int M_ = B_ * S_;  // 8192
// softmax scale folded into Q at projection time: 1/8 * log2(e), applied in f32
#define QSCALE 0.18033688f

// ---------------- convert f32 -> f16 (x and the 4 weights in one launch) ----------------
__global__ __launch_bounds__(256) void cvt_all(
    const float* __restrict__ x, const float* __restrict__ wq,
    const float* __restrict__ wk, const float* __restrict__ wv,
    const float* __restrict__ wo, _Float16* __restrict__ xb,
    _Float16* __restrict__ wb /* 4 weights contiguous */) {
  int bx = blockIdx.x;
  const float* src;
  _Float16* dst;
  long i;
  if (bx < 4096) {
    src = x; dst = xb; i = (long)bx * 256 + threadIdx.x;
  } else {
    int seg = (bx - 4096) >> 9;
    src = seg == 0 ? wq : seg == 1 ? wk : seg == 2 ? wv : wo;
    dst = wb + (long)seg * D_ * D_;
    i = (long)((bx - 4096) & 511) * 256 + threadIdx.x;
  }
  const float4* s4 = (const float4*)src;
  float4 a = s4[2 * i], b = s4[2 * i + 1];
  half8 o = {(_Float16)a.x, (_Float16)a.y, (_Float16)a.z, (_Float16)a.w,
             (_Float16)b.x, (_Float16)b.y, (_Float16)b.z, (_Float16)b.w};
  *(half8*)(dst + 8 * i) = o;
}

// ---------------- shared GEMM core: C(128x128) = A[M][1024] * W[1024-rows][1024]^T ------
// LDS layout [row][32] fp16, 16B-chunk swizzle: slot c holds global chunk c^(row&3).
__device__ __forceinline__ void gemm_core(const _Float16* __restrict__ A,
                                          const _Float16* __restrict__ W,
                                          _Float16* As, _Float16* Bs, long m0,
                                          long n0, int t, f32x4 acc[4][4]) {
  const int lane = t & 63, w = t >> 6, wr = w >> 1, wc = w & 1;
  const int r16 = lane & 15, g = lane >> 4;
  const int srow = t >> 2, schunk = t & 3;
  const int sc = schunk ^ (srow & 3);
  const _Float16* Ap = A + (m0 + srow) * D_ + sc * 8;
  const _Float16* Wp = W + (n0 + srow) * D_ + sc * 8;
  _Float16* Ad = As + srow * 32 + schunk * 8;
  _Float16* Bd = Bs + srow * 32 + schunk * 8;
  for (int k0 = 0; k0 < D_; k0 += 32) {
    GLOAD16(Ap + k0, Ad);
    GLOAD16(Ap + 64 * D_ + k0, Ad + 64 * 32);
    GLOAD16(Wp + k0, Bd);
    GLOAD16(Wp + 64 * D_ + k0, Bd + 64 * 32);
    __syncthreads();
    half8 af[4], bf[4];
#pragma unroll
    for (int i = 0; i < 4; ++i) {
      int ra = wr * 64 + i * 16 + r16;
      int rb = wc * 64 + i * 16 + r16;
      af[i] = *(const half8*)(As + ra * 32 + ((g ^ (ra & 3)) * 8));
      bf[i] = *(const half8*)(Bs + rb * 32 + ((g ^ (rb & 3)) * 8));
    }
#pragma unroll
    for (int i = 0; i < 4; ++i)
#pragma unroll
      for (int j = 0; j < 4; ++j)
        acc[i][j] =
            __builtin_amdgcn_mfma_f32_16x16x32_f16(af[i], bf[j], acc[i][j], 0, 0, 0);
    __syncthreads();
  }
}

// ---------------- fused QKV projection ----------------
// grid (64, 24): y>>3 selects {Q,K,V}.
// Q is pre-scaled by QSCALE (f32, before fp16 cvt) so attn does p = 2^s.
// V is written transposed AND s-permuted within each 64-block:
//   s6 = kn*16+g*4+r  ->  sigma = (kn>>1)*32 + g*8 + (kn&1)*4 + r
// so attn's PV b128 read uses chunk index ch = j2*4+g — the exact index
// structure of the QK reads, which measure ZERO bank conflicts.
__global__ __launch_bounds__(256, 2) void gemm_qkv(
    const _Float16* __restrict__ A, const _Float16* __restrict__ Wq,
    const _Float16* __restrict__ Wk, const _Float16* __restrict__ Wv,
    _Float16* __restrict__ Qo, _Float16* __restrict__ Ko,
    _Float16* __restrict__ Vt) {
  __shared__ _Float16 As[128 * 32], Bs[128 * 32];
  const int t = threadIdx.x;
  const int sel = blockIdx.y >> 3;
  const _Float16* W = sel == 0 ? Wq : (sel == 1 ? Wk : Wv);
  long m0 = (long)blockIdx.x * 128;
  long n0 = (long)(blockIdx.y & 7) * 128;
  f32x4 acc[4][4] = {};
  gemm_core(A, W, As, Bs, m0, n0, t, acc);
  const int lane = t & 63, w = t >> 6, wr = w >> 1, wc = w & 1;
  const int r16 = lane & 15, g = lane >> 4;
  if (sel < 2) {
    _Float16* C = sel == 0 ? Qo : Ko;
    const float qs = sel == 0 ? QSCALE : 1.0f;
#pragma unroll
    for (int i = 0; i < 4; ++i)
#pragma unroll
      for (int j = 0; j < 4; ++j)
#pragma unroll
        for (int r = 0; r < 4; ++r) {
          long mr = m0 + wr * 64 + i * 16 + g * 4 + r;
          long nc = n0 + wc * 64 + j * 16 + r16;
          C[mr * D_ + nc] = (_Float16)(acc[i][j][r] * qs);
        }
  } else {
#pragma unroll
    for (int i = 0; i < 4; ++i)
#pragma unroll
      for (int j = 0; j < 4; ++j)
#pragma unroll
        for (int r = 0; r < 4; ++r) {
          long mr = m0 + wr * 64 + i * 16 + g * 4 + r;
          long nc = n0 + wc * 64 + j * 16 + r16;
          long bb = mr >> 11, ss = mr & 2047;
          int s6 = (int)(ss & 63);
          int kn = s6 >> 4, gg = (s6 >> 2) & 3, rr = s6 & 3;
          int sp = (kn >> 1) * 32 + gg * 8 + (kn & 1) * 4 + rr;
          long ssp = (ss & ~63L) | sp;
          long hh = nc >> 6, dd = nc & 63;
          Vt[(((bb * 16 + hh) * 64 + dd) << 11) + ssp] = (_Float16)acc[i][j][r];
        }
  }
}

// ---------------- output projection (f32 out) ----------------
__global__ __launch_bounds__(256, 2) void gemm_out(const _Float16* __restrict__ A,
                                                   const _Float16* __restrict__ W,
                                                   float* __restrict__ C) {
  __shared__ _Float16 As[128 * 32], Bs[128 * 32];
  const int t = threadIdx.x;
  long m0 = (long)blockIdx.x * 128;
  long n0 = (long)blockIdx.y * 128;
  f32x4 acc[4][4] = {};
  gemm_core(A, W, As, Bs, m0, n0, t, acc);
  const int lane = t & 63, w = t >> 6, wr = w >> 1, wc = w & 1;
  const int r16 = lane & 15, g = lane >> 4;
#pragma unroll
  for (int i = 0; i < 4; ++i)
#pragma unroll
    for (int j = 0; j < 4; ++j)
#pragma unroll
      for (int r = 0; r < 4; ++r) {
        long mr = m0 + wr * 64 + i * 16 + g * 4 + r;
        long nc = n0 + wc * 64 + j * 16 + r16;
        C[mr * D_ + nc] = acc[i][j][r];
      }
}

// ---------------- flash attention (flat softmax, register-resident P) -------------------
// grid (8, 64): x = q-tile of 256 rows, y = (b*16+h). 8 waves x 32 q-rows.
// Swapped QK^T -> lane holds P^T(k=g*4+r, q=r16) = A-frag of mfma_16x16x16f16.
// R10 ILP fix: only 4 waves/SIMD (grid-limited) -> MFMA latency was exposed
// by distance-2 accumulator chains (~17 cyc/MFMA effective). Reordered so
// every accumulator is touched at distance 8: QK ks-outer/kn-inner; PV
// preloads all 8 V half8s then loops j2->half->mi->ni. Per-accumulator
// k-order is UNCHANGED -> bitwise-identical results. T5 setprio around
// MFMA clusters (role-split waves exist; +4-7% measured on attn).
// Sync discipline (R3-verified): counted vmcnt keeps next tile's loads in
// flight across the barrier; sched_barrier(0) brackets the compute phase;
// explicit lgkmcnt(0) before the end barrier closes the W-A-R window.
__global__ __launch_bounds__(512, 4) void attn_kernel(
    const _Float16* __restrict__ Q, const _Float16* __restrict__ K,
    const _Float16* __restrict__ Vt, _Float16* __restrict__ Ctx) {
  __shared__ _Float16 Ks[2][64 * 64], Vs[2][64 * 64];
  const int t = threadIdx.x, lane = t & 63, w = t >> 6;
  const int r16 = lane & 15, g = lane >> 4;
  const int q0 = blockIdx.x * 256;
  const int bh = blockIdx.y;
  const int b = bh >> 4, h = bh & 15;
  const long qkbase = ((long)b * S_) * D_ + h * 64;
  const long vtbase = (long)bh * 64 * S_;

  // Q fragments from global (already scaled by QSCALE at projection).
  // Used as the B operand of the swapped QK: B[q=lane&15][d=g*8+j].
  half8 qf[2][2];
#pragma unroll
  for (int mi = 0; mi < 2; ++mi)
#pragma unroll
    for (int ks = 0; ks < 2; ++ks) {
      int row = q0 + w * 32 + mi * 16 + r16;
      qf[mi][ks] = *(const half8*)(Q + qkbase + (long)row * D_ + ks * 32 + g * 8);
    }
  // drain Q loads so in-loop vmcnt counting is exact
  asm volatile("s_waitcnt vmcnt(0)" ::: "memory");

  f32x4 ctx[2][4] = {};
  float lsum[2] = {0.f, 0.f};  // per-lane: q = r16, k-slice (g, regs)

  // staging: 512 threads cover all 64 rows of K and V (1 gload each per tile)
  const int srowt = t >> 3, schunk = t & 7;
  const int sc = schunk ^ (srowt & 7);
  const _Float16* Kg = K + qkbase + (long)srowt * D_ + sc * 8;
  const _Float16* Vg = Vt + vtbase + (long)srowt * S_ + sc * 8;

#define STAGE(kt, buf)                                                  \
  do {                                                                  \
    GLOAD16(Kg + (long)(kt)*64 * D_, &Ks[buf][srowt * 64 + schunk * 8]); \
    GLOAD16(Vg + (kt)*64, &Vs[buf][srowt * 64 + schunk * 8]);            \
  } while (0)

  STAGE(0, 0);
  constexpr int NT = S_ / 64;
  for (int kt = 0; kt < NT; ++kt) {
    const int cur = kt & 1;
    if (kt + 1 < NT) {
      STAGE(kt + 1, cur ^ 1);
      asm volatile("s_waitcnt vmcnt(2)" ::: "memory");  // cur tile landed; next in flight
    } else {
      asm volatile("s_waitcnt vmcnt(0)" ::: "memory");
    }
    __builtin_amdgcn_s_barrier();
    MEMFENCE;
    __builtin_amdgcn_sched_barrier(0);  // nothing hoists above the barrier
    const _Float16* Kc = Ks[cur];
    const _Float16* Vc = Vs[cur];

    // S^T = K Q^T: sf[kn][mi], row=k=g*4+r, col=q=r16.
    // ks outer / kn inner: each sf[kn][mi] touched once per 8-MFMA group.
    f32x4 sf[4][2] = {};
    __builtin_amdgcn_s_setprio(1);
#pragma unroll
    for (int ks = 0; ks < 2; ++ks) {
      half8 kf[4];
#pragma unroll
      for (int kn = 0; kn < 4; ++kn) {
        int row = kn * 16 + r16;
        int ch = ks * 4 + g;
        kf[kn] = *(const half8*)(Kc + row * 64 + ((ch ^ (row & 7)) * 8));
      }
#pragma unroll
      for (int kn = 0; kn < 4; ++kn) {
        sf[kn][0] = __builtin_amdgcn_mfma_f32_16x16x32_f16(kf[kn], qf[0][ks], sf[kn][0], 0, 0, 0);
        sf[kn][1] = __builtin_amdgcn_mfma_f32_16x16x32_f16(kf[kn], qf[1][ks], sf[kn][1], 0, 0, 0);
      }
    }
    __builtin_amdgcn_s_setprio(0);

    // flat softmax in-register: p = 2^s (native TRANS pipe); pack into PV A-frags
    half4 pt[4][2];
#pragma unroll
    for (int kn = 0; kn < 4; ++kn)
#pragma unroll
      for (int mi = 0; mi < 2; ++mi) {
        float p0 = exp2_fast(sf[kn][mi][0]);
        float p1 = exp2_fast(sf[kn][mi][1]);
        float p2 = exp2_fast(sf[kn][mi][2]);
        float p3 = exp2_fast(sf[kn][mi][3]);
        lsum[mi] += (p0 + p1) + (p2 + p3);
        half4 pk = {(_Float16)p0, (_Float16)p1, (_Float16)p2, (_Float16)p3};
        pt[kn][mi] = pk;
      }

    // ctx += P V. Preload all 8 V b128s, then j2->half->mi->ni: every
    // ctx[mi][ni] at dependency distance 8; per-acc k-order still 0,1,2,3.
    half8 vf[4][2];
#pragma unroll
    for (int ni = 0; ni < 4; ++ni) {
      int row = ni * 16 + r16;  // d-row of Vs
#pragma unroll
      for (int j2 = 0; j2 < 2; ++j2) {
        int ch = j2 * 4 + g;  // same index structure as QK reads (0 conflicts)
        vf[ni][j2] = *(const half8*)(Vc + row * 64 + ((ch ^ (row & 7)) * 8));
      }
    }
    __builtin_amdgcn_s_setprio(1);
#pragma unroll
    for (int j2 = 0; j2 < 2; ++j2)
#pragma unroll
      for (int hf = 0; hf < 2; ++hf)
#pragma unroll
        for (int mi = 0; mi < 2; ++mi)
#pragma unroll
          for (int ni = 0; ni < 4; ++ni) {
            half4 vh = hf == 0
                           ? __builtin_shufflevector(vf[ni][j2], vf[ni][j2], 0, 1, 2, 3)
                           : __builtin_shufflevector(vf[ni][j2], vf[ni][j2], 4, 5, 6, 7);
            ctx[mi][ni] = __builtin_amdgcn_mfma_f32_16x16x16f16(pt[2 * j2 + hf][mi], vh,
                                                                ctx[mi][ni], 0, 0, 0);
          }
    __builtin_amdgcn_s_setprio(0);
    __builtin_amdgcn_sched_barrier(0);  // nothing (incl. MFMA) sinks below here
    asm volatile("s_waitcnt lgkmcnt(0)" ::: "memory");  // all my LDS reads sampled
    MEMFENCE;
    __builtin_amdgcn_s_barrier();
    MEMFENCE;
  }
#undef STAGE

  // row sums: lanes sharing q=r16 live at lane ^ 16, ^32 -> reduce, then
  // redistribute to the ctx layout (q = g*4+r) via intra-16 shfl.
  float linv[2];
#pragma unroll
  for (int mi = 0; mi < 2; ++mi) {
    float v = lsum[mi];
    v += __shfl_xor(v, 16);
    v += __shfl_xor(v, 32);
    linv[mi] = 1.f / v;
  }
#pragma unroll
  for (int mi = 0; mi < 2; ++mi)
#pragma unroll
    for (int r = 0; r < 4; ++r) {
      float inv = __shfl(linv[mi], g * 4 + r, 16);
      long qrow = (long)b * S_ + q0 + w * 32 + mi * 16 + g * 4 + r;
#pragma unroll
      for (int ni = 0; ni < 4; ++ni)
        Ctx[qrow * D_ + h * 64 + ni * 16 + r16] = (_Float16)(ctx[mi][ni][r] * inv);
    }
}

extern "C" void kernel_launch(void* const* d_in, const int* in_sizes, int n_in,
                              void* d_out, int out_size, void* d_ws, size_t ws_size,
                              hipStream_t stream) {
  (void)in_sizes; (void)n_in; (void)out_size; (void)ws_size;
  const float* x = (const float*)d_in[0];
  const float* Wq = (const float*)d_in[1];
  const float* Wk = (const float*)d_in[2];
  const float* Wv = (const float*)d_in[3];
  const float* Wo = (const float*)d_in[4];
  char* ws = (char*)d_ws;
  _Float16* xb = (_Float16*)ws;                               // 16 MB  [8192][1024]
  _Float16* wb = (_Float16*)(ws + (size_t)16 * 1024 * 1024);  // 8 MB   4x[1024][1024]
  _Float16* wqb = wb;
  _Float16* wkb = wb + (size_t)D_ * D_;
  _Float16* wvb = wb + (size_t)2 * D_ * D_;
  _Float16* wob = wb + (size_t)3 * D_ * D_;
  _Float16* qb = (_Float16*)(ws + (size_t)24 * 1024 * 1024);  // 16 MB  [8192][1024]
  _Float16* kb = qb + (size_t)M_ * D_;                        // 16 MB
  _Float16* vtb = kb + (size_t)M_ * D_;                       // 16 MB  [64][64][2048] s-permuted
  _Float16* ctxb = vtb + (size_t)M_ * D_;                     // 16 MB

  cvt_all<<<4096 + 4 * 512, 256, 0, stream>>>(x, Wq, Wk, Wv, Wo, xb, wb);
  gemm_qkv<<<dim3(64, 24), 256, 0, stream>>>(xb, wqb, wkb, wvb, qb, kb, vtb);
  attn_kernel<<<dim3(8, 64), 512, 0, stream>>>(qb, kb, vtb, ctxb);
  gemm_out<<<dim3(64, 8), 256, 0, stream>>>(ctxb, wob, (float*)d_out);
}

// Round 12
// 168.916 us; speedup vs baseline: 1.1507x; 1.1507x over previous
//
#include <hip/hip_runtime.h>

typedef _Float16 half8 __attribute__((ext_vector_type(8)));
typedef _Float16 half4 __attribute__((ext_vector_type(4)));
typedef float f32x4 __attribute__((ext_vector_type(4)));

#define GLOAD16(gptr, lptr)                                                               \
  __builtin_amdgcn_global_load_lds((const __attribute__((address_space(1))) void*)(gptr), \
                                   (__attribute__((address_space(3))) void*)(lptr), 16, 0, 0)

// compiler-level memory fence (no instructions): pins LDS/global op ordering
// around raw s_barrier, which is NOT an IR-level memory fence.
#define MEMFENCE asm volatile("" ::: "memory")

// 2^x on the native TRANS pipe via the builtin (compiler inserts the required
// TRANS-hazard wait states; raw inline-asm v_exp_f32 NaN'd in R9).
__device__ __forceinline__ float exp2_fast(float x) {
#if __has_builtin(__builtin_amdgcn_exp2f)
  return __builtin_amdgcn_exp2f(x);
#else
  float r;
  asm("v_exp_f32 %0, %1\n\ts_nop 3" : "=v"(r) : "v"(x));
  return r;
#endif
}

constexpr int B_ = 4, S_ = 2048, D_ = 1024;
constexpr int M_ = B_ * S_;  // 8192
// softmax scale folded into Q at projection time: 1/8 * log2(e), applied in f32
#define QSCALE 0.18033688f

// ---------------- convert f32 -> f16 (x and the 4 weights in one launch) ----------------
__global__ __launch_bounds__(256) void cvt_all(
    const float* __restrict__ x, const float* __restrict__ wq,
    const float* __restrict__ wk, const float* __restrict__ wv,
    const float* __restrict__ wo, _Float16* __restrict__ xb,
    _Float16* __restrict__ wb /* 4 weights contiguous */) {
  int bx = blockIdx.x;
  const float* src;
  _Float16* dst;
  long i;
  if (bx < 4096) {
    src = x; dst = xb; i = (long)bx * 256 + threadIdx.x;
  } else {
    int seg = (bx - 4096) >> 9;
    src = seg == 0 ? wq : seg == 1 ? wk : seg == 2 ? wv : wo;
    dst = wb + (long)seg * D_ * D_;
    i = (long)((bx - 4096) & 511) * 256 + threadIdx.x;
  }
  const float4* s4 = (const float4*)src;
  float4 a = s4[2 * i], b = s4[2 * i + 1];
  half8 o = {(_Float16)a.x, (_Float16)a.y, (_Float16)a.z, (_Float16)a.w,
             (_Float16)b.x, (_Float16)b.y, (_Float16)b.z, (_Float16)b.w};
  *(half8*)(dst + 8 * i) = o;
}

// ---------------- shared GEMM core: C(128x128) = A[M][1024] * W[1024-rows][1024]^T ------
// R12: BK=64. LDS rows are 128B with the attn-verified 8-slot chunk swizzle
// (slot c holds global chunk c^(row&7)); fragment reads use ch = ks*4+g —
// measured ZERO bank conflicts in attn (old BK=32/4-slot layout was 4-way).
// Half the K-iterations -> half the barrier drains.
__device__ __forceinline__ void gemm_core(const _Float16* __restrict__ A,
                                          const _Float16* __restrict__ W,
                                          _Float16* As, _Float16* Bs, long m0,
                                          long n0, int t, f32x4 acc[4][4]) {
  const int lane = t & 63, w = t >> 6, wr = w >> 1, wc = w & 1;
  const int r16 = lane & 15, g = lane >> 4;
  const int srow = t >> 3, schunk = t & 7;        // 32 rows per issue, 8 chunks/row
  const int sc = schunk ^ (srow & 7);             // inverse (involution) of read swizzle
  const _Float16* Ap = A + (m0 + srow) * D_ + sc * 8;
  const _Float16* Wp = W + (n0 + srow) * D_ + sc * 8;
  _Float16* Ad = As + srow * 64 + schunk * 8;
  _Float16* Bd = Bs + srow * 64 + schunk * 8;
  for (int k0 = 0; k0 < D_; k0 += 64) {
#pragma unroll
    for (int p = 0; p < 4; ++p) {
      GLOAD16(Ap + k0 + (long)p * 32 * D_, Ad + p * 32 * 64);
      GLOAD16(Wp + k0 + (long)p * 32 * D_, Bd + p * 32 * 64);
    }
    __syncthreads();
#pragma unroll
    for (int ks = 0; ks < 2; ++ks) {
      half8 af[4], bf[4];
#pragma unroll
      for (int i = 0; i < 4; ++i) {
        int ra = wr * 64 + i * 16 + r16;
        int rb = wc * 64 + i * 16 + r16;
        int ch = ks * 4 + g;
        af[i] = *(const half8*)(As + ra * 64 + ((ch ^ (ra & 7)) * 8));
        bf[i] = *(const half8*)(Bs + rb * 64 + ((ch ^ (rb & 7)) * 8));
      }
#pragma unroll
      for (int i = 0; i < 4; ++i)
#pragma unroll
        for (int j = 0; j < 4; ++j)
          acc[i][j] =
              __builtin_amdgcn_mfma_f32_16x16x32_f16(af[i], bf[j], acc[i][j], 0, 0, 0);
    }
    __syncthreads();
  }
}

// ---------------- fused QKV projection ----------------
// grid (64, 24): y>>3 selects {Q,K,V}.
// Q is pre-scaled by QSCALE (f32, before fp16 cvt) so attn does p = 2^s.
// V is written transposed AND s-permuted within each 64-block:
//   s6 = kn*16+g*4+r  ->  sigma = (kn>>1)*32 + g*8 + (kn&1)*4 + r
// so attn's PV b128 read uses chunk index ch = j2*4+g — the exact index
// structure of the QK reads, which measure ZERO bank conflicts.
__global__ __launch_bounds__(256, 2) void gemm_qkv(
    const _Float16* __restrict__ A, const _Float16* __restrict__ Wq,
    const _Float16* __restrict__ Wk, const _Float16* __restrict__ Wv,
    _Float16* __restrict__ Qo, _Float16* __restrict__ Ko,
    _Float16* __restrict__ Vt) {
  __shared__ _Float16 As[128 * 64], Bs[128 * 64];
  const int t = threadIdx.x;
  const int sel = blockIdx.y >> 3;
  const _Float16* W = sel == 0 ? Wq : (sel == 1 ? Wk : Wv);
  long m0 = (long)blockIdx.x * 128;
  long n0 = (long)(blockIdx.y & 7) * 128;
  f32x4 acc[4][4] = {};
  gemm_core(A, W, As, Bs, m0, n0, t, acc);
  const int lane = t & 63, w = t >> 6, wr = w >> 1, wc = w & 1;
  const int r16 = lane & 15, g = lane >> 4;
  if (sel < 2) {
    _Float16* C = sel == 0 ? Qo : Ko;
    const float qs = sel == 0 ? QSCALE : 1.0f;
#pragma unroll
    for (int i = 0; i < 4; ++i)
#pragma unroll
      for (int j = 0; j < 4; ++j)
#pragma unroll
        for (int r = 0; r < 4; ++r) {
          long mr = m0 + wr * 64 + i * 16 + g * 4 + r;
          long nc = n0 + wc * 64 + j * 16 + r16;
          C[mr * D_ + nc] = (_Float16)(acc[i][j][r] * qs);
        }
  } else {
#pragma unroll
    for (int i = 0; i < 4; ++i)
#pragma unroll
      for (int j = 0; j < 4; ++j)
#pragma unroll
        for (int r = 0; r < 4; ++r) {
          long mr = m0 + wr * 64 + i * 16 + g * 4 + r;
          long nc = n0 + wc * 64 + j * 16 + r16;
          long bb = mr >> 11, ss = mr & 2047;
          int s6 = (int)(ss & 63);
          int kn = s6 >> 4, gg = (s6 >> 2) & 3, rr = s6 & 3;
          int sp = (kn >> 1) * 32 + gg * 8 + (kn & 1) * 4 + rr;
          long ssp = (ss & ~63L) | sp;
          long hh = nc >> 6, dd = nc & 63;
          Vt[(((bb * 16 + hh) * 64 + dd) << 11) + ssp] = (_Float16)acc[i][j][r];
        }
  }
}

// ---------------- output projection (f32 out) ----------------
__global__ __launch_bounds__(256, 2) void gemm_out(const _Float16* __restrict__ A,
                                                   const _Float16* __restrict__ W,
                                                   float* __restrict__ C) {
  __shared__ _Float16 As[128 * 64], Bs[128 * 64];
  const int t = threadIdx.x;
  long m0 = (long)blockIdx.x * 128;
  long n0 = (long)blockIdx.y * 128;
  f32x4 acc[4][4] = {};
  gemm_core(A, W, As, Bs, m0, n0, t, acc);
  const int lane = t & 63, w = t >> 6, wr = w >> 1, wc = w & 1;
  const int r16 = lane & 15, g = lane >> 4;
#pragma unroll
  for (int i = 0; i < 4; ++i)
#pragma unroll
    for (int j = 0; j < 4; ++j)
#pragma unroll
      for (int r = 0; r < 4; ++r) {
        long mr = m0 + wr * 64 + i * 16 + g * 4 + r;
        long nc = n0 + wc * 64 + j * 16 + r16;
        C[mr * D_ + nc] = acc[i][j][r];
      }
}

// ---------------- flash attention (flat softmax, register-resident P) -------------------
// EXACT R10 code (measured 85 us, MfmaUtil 52%, 0 conflicts). R11's
// setprio+manual-reorder regressed (lockstep waves = m190's null case;
// compiler already interleaves the independent accumulator MFMAs).
// grid (8, 64): x = q-tile of 256 rows, y = (b*16+h). 8 waves x 32 q-rows.
// Swapped QK^T -> lane holds P^T(k=g*4+r, q=r16) = A-frag of mfma_16x16x16f16.
// p = 2^s via __builtin_amdgcn_exp2f (scale*log2e folded into Q at projection).
// PV: V s-permuted at producer -> b128 read with ch = j2*4+g (QK's proven
// conflict-free pattern); its half4s are the kt16=2j2 / 2j2+1 B-frags.
// Sync discipline (R3-verified): counted vmcnt keeps next tile's loads in
// flight across the barrier; sched_barrier(0) brackets the compute phase;
// explicit lgkmcnt(0) before the end barrier closes the W-A-R window.
__global__ __launch_bounds__(512, 4) void attn_kernel(
    const _Float16* __restrict__ Q, const _Float16* __restrict__ K,
    const _Float16* __restrict__ Vt, _Float16* __restrict__ Ctx) {
  __shared__ _Float16 Ks[2][64 * 64], Vs[2][64 * 64];
  const int t = threadIdx.x, lane = t & 63, w = t >> 6;
  const int r16 = lane & 15, g = lane >> 4;
  const int q0 = blockIdx.x * 256;
  const int bh = blockIdx.y;
  const int b = bh >> 4, h = bh & 15;
  const long qkbase = ((long)b * S_) * D_ + h * 64;
  const long vtbase = (long)bh * 64 * S_;

  // Q fragments from global (already scaled by QSCALE at projection).
  // Used as the B operand of the swapped QK: B[q=lane&15][d=g*8+j].
  half8 qf[2][2];
#pragma unroll
  for (int mi = 0; mi < 2; ++mi)
#pragma unroll
    for (int ks = 0; ks < 2; ++ks) {
      int row = q0 + w * 32 + mi * 16 + r16;
      qf[mi][ks] = *(const half8*)(Q + qkbase + (long)row * D_ + ks * 32 + g * 8);
    }
  // drain Q loads so in-loop vmcnt counting is exact
  asm volatile("s_waitcnt vmcnt(0)" ::: "memory");

  f32x4 ctx[2][4] = {};
  float lsum[2] = {0.f, 0.f};  // per-lane: q = r16, k-slice (g, regs)

  // staging: 512 threads cover all 64 rows of K and V (1 gload each per tile)
  const int srowt = t >> 3, schunk = t & 7;
  const int sc = schunk ^ (srowt & 7);
  const _Float16* Kg = K + qkbase + (long)srowt * D_ + sc * 8;
  const _Float16* Vg = Vt + vtbase + (long)srowt * S_ + sc * 8;

#define STAGE(kt, buf)                                                  \
  do {                                                                  \
    GLOAD16(Kg + (long)(kt)*64 * D_, &Ks[buf][srowt * 64 + schunk * 8]); \
    GLOAD16(Vg + (kt)*64, &Vs[buf][srowt * 64 + schunk * 8]);            \
  } while (0)

  STAGE(0, 0);
  constexpr int NT = S_ / 64;
  for (int kt = 0; kt < NT; ++kt) {
    const int cur = kt & 1;
    if (kt + 1 < NT) {
      STAGE(kt + 1, cur ^ 1);
      asm volatile("s_waitcnt vmcnt(2)" ::: "memory");  // cur tile landed; next in flight
    } else {
      asm volatile("s_waitcnt vmcnt(0)" ::: "memory");
    }
    __builtin_amdgcn_s_barrier();
    MEMFENCE;
    __builtin_amdgcn_sched_barrier(0);  // nothing hoists above the barrier
    const _Float16* Kc = Ks[cur];
    const _Float16* Vc = Vs[cur];

    // S^T = K Q^T: sf[kn][mi], row=k=g*4+r, col=q=r16
    f32x4 sf[4][2] = {};
#pragma unroll
    for (int kn = 0; kn < 4; ++kn) {
#pragma unroll
      for (int ks = 0; ks < 2; ++ks) {
        int row = kn * 16 + r16;
        int ch = ks * 4 + g;
        half8 kf = *(const half8*)(Kc + row * 64 + ((ch ^ (row & 7)) * 8));
        sf[kn][0] = __builtin_amdgcn_mfma_f32_16x16x32_f16(kf, qf[0][ks], sf[kn][0], 0, 0, 0);
        sf[kn][1] = __builtin_amdgcn_mfma_f32_16x16x32_f16(kf, qf[1][ks], sf[kn][1], 0, 0, 0);
      }
    }

    // flat softmax in-register: p = 2^s (native TRANS pipe); pack into PV A-frags
    half4 pt[4][2];
#pragma unroll
    for (int kn = 0; kn < 4; ++kn)
#pragma unroll
      for (int mi = 0; mi < 2; ++mi) {
        float p0 = exp2_fast(sf[kn][mi][0]);
        float p1 = exp2_fast(sf[kn][mi][1]);
        float p2 = exp2_fast(sf[kn][mi][2]);
        float p3 = exp2_fast(sf[kn][mi][3]);
        lsum[mi] += (p0 + p1) + (p2 + p3);
        half4 pk = {(_Float16)p0, (_Float16)p1, (_Float16)p2, (_Float16)p3};
        pt[kn][mi] = pk;
      }

    // ctx += P V via K=16 MFMAs; one b128 V read per (ni,j2) covers kt16=2j2,2j2+1
#pragma unroll
    for (int ni = 0; ni < 4; ++ni) {
      int row = ni * 16 + r16;  // d-row of Vs
#pragma unroll
      for (int j2 = 0; j2 < 2; ++j2) {
        int ch = j2 * 4 + g;  // same index structure as QK reads (0 conflicts)
        half8 vf8 = *(const half8*)(Vc + row * 64 + ((ch ^ (row & 7)) * 8));
        half4 v0 = __builtin_shufflevector(vf8, vf8, 0, 1, 2, 3);
        half4 v1 = __builtin_shufflevector(vf8, vf8, 4, 5, 6, 7);
        ctx[0][ni] = __builtin_amdgcn_mfma_f32_16x16x16f16(pt[2 * j2][0], v0, ctx[0][ni], 0, 0, 0);
        ctx[1][ni] = __builtin_amdgcn_mfma_f32_16x16x16f16(pt[2 * j2][1], v0, ctx[1][ni], 0, 0, 0);
        ctx[0][ni] = __builtin_amdgcn_mfma_f32_16x16x16f16(pt[2 * j2 + 1][0], v1, ctx[0][ni], 0, 0, 0);
        ctx[1][ni] = __builtin_amdgcn_mfma_f32_16x16x16f16(pt[2 * j2 + 1][1], v1, ctx[1][ni], 0, 0, 0);
      }
    }
    __builtin_amdgcn_sched_barrier(0);  // nothing (incl. MFMA) sinks below here
    asm volatile("s_waitcnt lgkmcnt(0)" ::: "memory");  // all my LDS reads sampled
    MEMFENCE;
    __builtin_amdgcn_s_barrier();
    MEMFENCE;
  }
#undef STAGE

  // row sums: lanes sharing q=r16 live at lane ^ 16, ^32 -> reduce, then
  // redistribute to the ctx layout (q = g*4+r) via intra-16 shfl.
  float linv[2];
#pragma unroll
  for (int mi = 0; mi < 2; ++mi) {
    float v = lsum[mi];
    v += __shfl_xor(v, 16);
    v += __shfl_xor(v, 32);
    linv[mi] = 1.f / v;
  }
#pragma unroll
  for (int mi = 0; mi < 2; ++mi)
#pragma unroll
    for (int r = 0; r < 4; ++r) {
      float inv = __shfl(linv[mi], g * 4 + r, 16);
      long qrow = (long)b * S_ + q0 + w * 32 + mi * 16 + g * 4 + r;
#pragma unroll
      for (int ni = 0; ni < 4; ++ni)
        Ctx[qrow * D_ + h * 64 + ni * 16 + r16] = (_Float16)(ctx[mi][ni][r] * inv);
    }
}

extern "C" void kernel_launch(void* const* d_in, const int* in_sizes, int n_in,
                              void* d_out, int out_size, void* d_ws, size_t ws_size,
                              hipStream_t stream) {
  (void)in_sizes; (void)n_in; (void)out_size; (void)ws_size;
  const float* x = (const float*)d_in[0];
  const float* Wq = (const float*)d_in[1];
  const float* Wk = (const float*)d_in[2];
  const float* Wv = (const float*)d_in[3];
  const float* Wo = (const float*)d_in[4];
  char* ws = (char*)d_ws;
  _Float16* xb = (_Float16*)ws;                               // 16 MB  [8192][1024]
  _Float16* wb = (_Float16*)(ws + (size_t)16 * 1024 * 1024);  // 8 MB   4x[1024][1024]
  _Float16* wqb = wb;
  _Float16* wkb = wb + (size_t)D_ * D_;
  _Float16* wvb = wb + (size_t)2 * D_ * D_;
  _Float16* wob = wb + (size_t)3 * D_ * D_;
  _Float16* qb = (_Float16*)(ws + (size_t)24 * 1024 * 1024);  // 16 MB  [8192][1024]
  _Float16* kb = qb + (size_t)M_ * D_;                        // 16 MB
  _Float16* vtb = kb + (size_t)M_ * D_;                       // 16 MB  [64][64][2048] s-permuted
  _Float16* ctxb = vtb + (size_t)M_ * D_;                     // 16 MB

  cvt_all<<<4096 + 4 * 512, 256, 0, stream>>>(x, Wq, Wk, Wv, Wo, xb, wb);
  gemm_qkv<<<dim3(64, 24), 256, 0, stream>>>(xb, wqb, wkb, wvb, qb, kb, vtb);
  attn_kernel<<<dim3(8, 64), 512, 0, stream>>>(qb, kb, vtb, ctxb);
  gemm_out<<<dim3(64, 8), 256, 0, stream>>>(ctxb, wob, (float*)d_out);
}